// Round 8
// baseline (453.080 us; speedup 1.0000x reference)
//
#include <hip/hip_runtime.h>
#include <math.h>

#define NIMG 8
#define CIN 8
#define Hh 136
#define Ww 200
#define HW (Hh * Ww)
#define OH 272
#define OW 400
#define NINST 512
#define NPAR 169
#define TROWS 34
#define NTILES 8
#define LROWS 19
#define IT_PX 512
#define QSTRIDE 36                       /* words per 4-px group in hbuf (8*4+4 pad) */
#define HBUF_WORDS (128 * QSTRIDE)       /* 4608 floats = 18 KB */

#define PIN(x) asm volatile("" : "+v"(x))

// One block per (tile, instance): split-MLP (R7 structure, <=125 pinned
// weights/thread -> no spills) producing slog in LDS, then bilinear+sigmoid+
// dice directly from LDS. No logits round-trip through HBM.
__global__ __launch_bounds__(256, 2) void dmh_fused2(
    const float* __restrict__ feats,
    const float* __restrict__ pars,
    const float* __restrict__ iloc,
    const float* __restrict__ gt,
    const int* __restrict__ iminds,
    const int* __restrict__ lvls,
    float* __restrict__ part)
{
    __shared__ float hbuf[HBUF_WORDS];   // 18 KB hidden acts (one iteration)
    __shared__ float slog[LROWS * Ww];   // 15.2 KB low-res logits
    __shared__ float sred[12];

    const int n    = blockIdx.y;
    const int tile = blockIdx.x;
    const int tid  = threadIdx.x;
    const int qi   = tid & 127;          // quad index (phase 1)
    const int half = tid >> 7;           // channel half (phase 1)

    const float ix = iloc[2 * n + 0];
    const float iy = iloc[2 * n + 1];
    const int   im = iminds[n];
    const float invsoi = 1.0f / (float)(64 << lvls[n]);

    const float* pp = pars + n * NPAR;

    // ---- phase-1 weights: this thread's 4 output channels (44 values) ----
    float Wf[32], A0[4], Ax[4], Ay[4];
#pragma unroll
    for (int j = 0; j < 4; j++) {
        const int o = half * 4 + j;
        const float wx0 = pp[o * 10 + 0];
        const float wy0 = pp[o * 10 + 1];
        Ax[j] = -8.0f * invsoi * wx0;
        Ay[j] = -8.0f * invsoi * wy0;
        A0[j] = pp[152 + o] + (wx0 * (ix - 4.0f) + wy0 * (iy - 4.0f)) * invsoi;
#pragma unroll
        for (int c = 0; c < 8; c++) Wf[j * 8 + c] = pp[o * 10 + 2 + c];
    }
    // ---- phase-2 weights (81 values) ----
    float w1[64], w2[8], b1[8], b2;
#pragma unroll
    for (int i = 0; i < 64; i++) w1[i] = pp[80 + i];
#pragma unroll
    for (int i = 0; i < 8; i++)  w2[i] = pp[144 + i];
#pragma unroll
    for (int i = 0; i < 8; i++)  b1[i] = pp[160 + i];
    b2 = pp[168];

#pragma unroll
    for (int i = 0; i < 32; i++) PIN(Wf[i]);
#pragma unroll
    for (int i = 0; i < 4; i++) { PIN(A0[i]); PIN(Ax[i]); PIN(Ay[i]); }
#pragma unroll
    for (int i = 0; i < 64; i++) PIN(w1[i]);
#pragma unroll
    for (int i = 0; i < 8; i++) { PIN(w2[i]); PIN(b1[i]); }
    PIN(b2);

    const float sy = 135.0f / 271.0f;
    const float sx = 199.0f / 399.0f;

    const int oy0 = tile * TROWS;
    const int ly0 = (int)((float)oy0 * sy);
    int lyL = (int)((float)(oy0 + TROWS - 1) * sy) + 1;
    if (lyL > Hh - 1) lyL = Hh - 1;
    const int lycnt = lyL - ly0 + 1;
    const int npix  = lycnt * Ww;        // <= 3800

    const float* fb0 = feats + (size_t)im * (CIN * HW) + ly0 * Ww;

    // ================= MLP: fill slog[0..npix) =================
    const int niter = (npix + IT_PX - 1) / IT_PX;
    for (int it = 0; it < niter; it++) {
        const int base = it * IT_PX;
        const int cnt  = (npix - base < IT_PX) ? (npix - base) : IT_PX;

        // ---- phase 1: layer-1, 4 px x 4 ch per thread ----
        if (qi * 4 < cnt) {
            const int lpx = base + qi * 4;           // local px (row-major from ly0)
            const int yy  = lpx / Ww;
            const int x   = lpx - yy * Ww;
            const float yf = (float)(ly0 + yy);
            const float* fb = fb0 + lpx;
            float f[8][4];
#pragma unroll
            for (int c = 0; c < 8; c++) {
                const float4 t = *reinterpret_cast<const float4*>(fb + c * HW);
                f[c][0] = t.x; f[c][1] = t.y; f[c][2] = t.z; f[c][3] = t.w;
            }
            float* hb = &hbuf[qi * QSTRIDE + half * 4];
#pragma unroll
            for (int p = 0; p < 4; p++) {
                const float xf = (float)(x + p);
                float4 hv;
                float* hvp = (float*)&hv;
#pragma unroll
                for (int j = 0; j < 4; j++) {
                    float a = A0[j] + Ax[j] * xf + Ay[j] * yf;
#pragma unroll
                    for (int c = 0; c < 8; c++) a += Wf[j * 8 + c] * f[c][p];
                    hvp[j] = fmaxf(a, 0.0f);
                }
                *reinterpret_cast<float4*>(hb + p * 8) = hv;
            }
        }
        __syncthreads();

        // ---- phase 2: layers 2-3, 2 px per thread -> slog ----
#pragma unroll
        for (int s = 0; s < 2; s++) {
            const int pl = tid + s * 256;
            if (pl < cnt) {
                const int q = pl >> 2, p = pl & 3;
                const float* hb = &hbuf[q * QSTRIDE + p * 8];
                const float4 h0 = *reinterpret_cast<const float4*>(hb);
                const float4 h1 = *reinterpret_cast<const float4*>(hb + 4);
                const float hv[8] = { h0.x, h0.y, h0.z, h0.w, h1.x, h1.y, h1.z, h1.w };
                float lg = b2;
#pragma unroll
                for (int o = 0; o < 8; o++) {
                    float a = b1[o];
#pragma unroll
                    for (int c = 0; c < 8; c++) a += w1[o * 8 + c] * hv[c];
                    lg += w2[o] * fmaxf(a, 0.0f);
                }
                slog[base + pl] = lg;
            }
        }
        __syncthreads();
    }

    // ================= dice: bilinear + sigmoid + partial sums =================
    float aI = 0.0f, aS = 0.0f, aT = 0.0f;
    const float* gtn = gt + (size_t)n * (OH * OW) + (size_t)oy0 * OW;
    for (int g4 = tid; g4 < TROWS * (OW / 4); g4 += 256) {
        const int ry = g4 / 100;
        const int gx = (g4 - ry * 100) * 4;
        const int oy = oy0 + ry;
        const float ysf = (float)oy * sy;
        const int y0 = (int)ysf;
        const float wy = ysf - (float)y0;
        const int y1 = (y0 + 1 > Hh - 1) ? (Hh - 1) : (y0 + 1);
        int r0i = y0 - ly0, r1i = y1 - ly0;
        r0i = r0i < 0 ? 0 : (r0i > lycnt - 1 ? lycnt - 1 : r0i);
        r1i = r1i < 0 ? 0 : (r1i > lycnt - 1 ? lycnt - 1 : r1i);
        const float* s0 = &slog[r0i * Ww];
        const float* s1 = &slog[r1i * Ww];

        const float4 t4 = *reinterpret_cast<const float4*>(gtn + ry * OW + gx);
        const float tv[4] = { t4.x, t4.y, t4.z, t4.w };
#pragma unroll
        for (int p = 0; p < 4; p++) {
            const int ox = gx + p;
            const float xsf = (float)ox * sx;
            const int x0 = (int)xsf;
            const float wx = xsf - (float)x0;
            const int x1 = (x0 + 1 > Ww - 1) ? (Ww - 1) : (x0 + 1);
            const float v00 = s0[x0];
            const float v01 = s0[x1];
            const float v10 = s1[x0];
            const float v11 = s1[x1];
            const float top = v00 + wx * (v01 - v00);
            const float bot = v10 + wx * (v11 - v10);
            const float v   = top + wy * (bot - top);
            const float sg  = __fdividef(1.0f, 1.0f + __expf(-v));
            aI += sg * tv[p];
            aS += sg * sg;
            aT += tv[p];
        }
    }

#pragma unroll
    for (int off = 32; off > 0; off >>= 1) {
        aI += __shfl_down(aI, off, 64);
        aS += __shfl_down(aS, off, 64);
        aT += __shfl_down(aT, off, 64);
    }
    const int wv = tid >> 6;
    if ((tid & 63) == 0) {
        sred[wv * 3 + 0] = aI;
        sred[wv * 3 + 1] = aS;
        sred[wv * 3 + 2] = aT;
    }
    __syncthreads();
    if (tid == 0) {
        float* pt = part + (size_t)(n * NTILES + tile) * 3;
        pt[0] = sred[0] + sred[3] + sred[6] + sred[9];
        pt[1] = sred[1] + sred[4] + sred[7] + sred[10];
        pt[2] = sred[2] + sred[5] + sred[8] + sred[11];
    }
}

__global__ __launch_bounds__(256) void dmh_fin2(const float* __restrict__ part,
                                                float* __restrict__ out)
{
    const int i = blockIdx.x * 256 + threadIdx.x;
    if (i < NINST) {
        float I = 0.0f, S = 0.0f, T = 0.0f;
#pragma unroll
        for (int t = 0; t < NTILES; t++) {
            const float* pt = part + (size_t)(i * NTILES + t) * 3;
            I += pt[0]; S += pt[1]; T += pt[2];
        }
        out[i] = 1.0f - 2.0f * I / (S + T + 1e-5f);
    }
}

extern "C" void kernel_launch(void* const* d_in, const int* in_sizes, int n_in,
                              void* d_out, int out_size, void* d_ws, size_t ws_size,
                              hipStream_t stream) {
    const float* feats  = (const float*)d_in[0];
    const float* pars   = (const float*)d_in[1];
    const float* iloc   = (const float*)d_in[2];
    const float* gt     = (const float*)d_in[3];
    const int*   iminds = (const int*)d_in[4];
    const int*   lvls   = (const int*)d_in[5];

    float* part = (float*)d_ws;          // 512*8*3 floats = 48 KB
    dim3 grid(NTILES, NINST);
    dmh_fused2<<<grid, 256, 0, stream>>>(feats, pars, iloc, gt, iminds, lvls, part);
    dmh_fin2<<<(NINST + 255) / 256, 256, 0, stream>>>(part, (float*)d_out);
}